// Round 9
// baseline (314.395 us; speedup 1.0000x reference)
//
#include <hip/hip_runtime.h>

#define HD 128          // hidden dim (== DIN)
#define DDOC 512
#define TOUT 32
#define RB 16           // rows per block in gemm
#define SCANB 256
#define PROWS 64        // rows per block in pooling
#define HBLK 1024       // threads in CSR-build blocks
#define CHUNK 15008     // dst-nodes per LDS histogram chunk (60 KB)
#define NSLICE 16       // edge slices
constexpr float NEG_SLOPE = 0.2f;

// ---------- bf16 helpers ----------
__device__ __forceinline__ unsigned short f2bf(float f) {
    unsigned int b = __float_as_uint(f);
    b += 0x7fffu + ((b >> 16) & 1u);     // round-to-nearest-even
    return (unsigned short)(b >> 16);
}
__device__ __forceinline__ float bflo2f(unsigned int u) { return __uint_as_float(u << 16); }
__device__ __forceinline__ float bfhi2f(unsigned int u) { return __uint_as_float(u & 0xffff0000u); }

// ---------- init: zero pooled ----------
__global__ void k_init(float* __restrict__ pooled, int np) {
    int i = blockIdx.x * blockDim.x + threadIdx.x;
    if (i < np) pooled[i] = 0.f;
}

// ---------- tiled GEMM + fused alpha: h = x@W (bf16 out), alpha = h.a (fp32) ----------
__global__ void k_gemm_alpha(const float* __restrict__ x, const float* __restrict__ W,
                             const float* __restrict__ av_s, const float* __restrict__ av_d,
                             unsigned short* __restrict__ h, float* __restrict__ alp_s,
                             float* __restrict__ alp_d, int n) {
    int row0 = blockIdx.x * RB;
    int t = threadIdx.x;            // 0..255
    int c = t & (HD - 1);
    int rg = t >> 7;                // 0: rows 0-7, 1: rows 8-15

    __shared__ float xs[RB][HD];
    for (int i = t; i < RB * HD; i += 256) {
        int r = i >> 7, k = i & (HD - 1);
        int row = row0 + r;
        xs[r][k] = (row < n) ? x[row * HD + k] : 0.f;
    }
    __syncthreads();

    float acc[8] = {0.f, 0.f, 0.f, 0.f, 0.f, 0.f, 0.f, 0.f};
    for (int k = 0; k < HD; ++k) {
        float w = W[k * HD + c];
#pragma unroll
        for (int r = 0; r < 8; ++r) acc[r] = fmaf(xs[rg * 8 + r][k], w, acc[r]);
    }
#pragma unroll
    for (int r = 0; r < 8; ++r) {
        int row = row0 + rg * 8 + r;
        if (row < n) h[row * HD + c] = f2bf(acc[r]);
    }

    float as = av_s[c], ad = av_d[c];
    __shared__ float redS[4][8], redD[4][8];
    int wave = t >> 6, lane = t & 63;
#pragma unroll
    for (int r = 0; r < 8; ++r) {
        float vs = acc[r] * as;
        float vd = acc[r] * ad;
#pragma unroll
        for (int off = 32; off > 0; off >>= 1) {
            vs += __shfl_xor(vs, off);
            vd += __shfl_xor(vd, off);
        }
        if (lane == 0) { redS[wave][r] = vs; redD[wave][r] = vd; }
    }
    __syncthreads();
    if (t < RB) {
        int w0 = (t < 8) ? 0 : 2;
        int rr = t & 7;
        int row = row0 + t;
        if (row < n) {
            alp_s[row] = redS[w0][rr] + redS[w0 + 1][rr];
            alp_d[row] = redD[w0][rr] + redD[w0 + 1][rr];
        }
    }
}

// ---------- CSR build via LDS histograms (zero global atomics) ----------
// block = (slice s, chunk c). LDS-histogram slice's edges whose dst is in chunk.
__global__ void k_hist_lds(const int* __restrict__ ei, int E, int Etot, int n,
                           int slice_sz, int nchunk, int* __restrict__ cnt) {
    int s = blockIdx.x / nchunk;
    int c = blockIdx.x % nchunk;
    int base = c * CHUNK;
    int lim = n - base; if (lim > CHUNK) lim = CHUNK;
    __shared__ int hh[CHUNK];
    for (int i = threadIdx.x; i < lim; i += HBLK) hh[i] = 0;
    __syncthreads();
    int lo = s * slice_sz;
    int hi = lo + slice_sz; if (hi > Etot) hi = Etot;
    for (int j = lo + threadIdx.x; j < hi; j += HBLK) {
        int d = (j < E) ? ei[E + j] : (j - E);
        int r = d - base;
        if (r >= 0 && r < lim) atomicAdd(&hh[r], 1);     // LDS atomic, no return
    }
    __syncthreads();
    for (int i = threadIdx.x; i < lim; i += HBLK) cnt[s * n + base + i] = hh[i];
}

// per-node running sum across slices -> off[s][node], deg[node]
__global__ void k_nodeoff(const int* __restrict__ cnt, int* __restrict__ off,
                          int* __restrict__ deg, int n) {
    int i = blockIdx.x * blockDim.x + threadIdx.x;
    if (i >= n) return;
    int run = 0;
#pragma unroll
    for (int s = 0; s < NSLICE; ++s) {
        int v = cnt[s * n + i];
        off[s * n + i] = run;
        run += v;
    }
    deg[i] = run;
}

// ---------- 3-phase device-wide exclusive scan of deg -> ptr ----------
__global__ void k_scan_part(const int* __restrict__ deg, int* __restrict__ bsum, int n) {
    int t = threadIdx.x;
    int i = blockIdx.x * SCANB + t;
    int v = (i < n) ? deg[i] : 0;
#pragma unroll
    for (int off = 32; off > 0; off >>= 1) v += __shfl_xor(v, off);
    __shared__ int red[4];
    if ((t & 63) == 0) red[t >> 6] = v;
    __syncthreads();
    if (t == 0) bsum[blockIdx.x] = red[0] + red[1] + red[2] + red[3];
}

__global__ void k_scan_bsum(int* __restrict__ bsum, int nb) {
    __shared__ int part[SCANB];
    int t = threadIdx.x;
    int v = (t < nb) ? bsum[t] : 0;
    part[t] = v;
    __syncthreads();
    for (int off = 1; off < SCANB; off <<= 1) {
        int u = (t >= off) ? part[t - off] : 0;
        __syncthreads();
        part[t] += u;
        __syncthreads();
    }
    if (t < nb) bsum[t] = part[t] - v;   // exclusive
}

__global__ void k_scan_final(const int* __restrict__ deg, const int* __restrict__ bsum,
                             int* __restrict__ ptr, int n, int total) {
    __shared__ int part[SCANB];
    int t = threadIdx.x;
    int i = blockIdx.x * SCANB + t;
    int v = (i < n) ? deg[i] : 0;
    part[t] = v;
    __syncthreads();
    for (int off = 1; off < SCANB; off <<= 1) {
        int u = (t >= off) ? part[t - off] : 0;
        __syncthreads();
        part[t] += u;
        __syncthreads();
    }
    if (i < n) ptr[i] = bsum[blockIdx.x] + part[t] - v;
    if (i == n - 1) ptr[n] = total;
}

// ---------- fill: LDS local ranks + precomputed slice offsets ----------
__global__ void k_fill_lds(const int* __restrict__ ei, int E, int Etot, int n,
                           int slice_sz, int nchunk, const int* __restrict__ ptr,
                           const int* __restrict__ off, int* __restrict__ col) {
    int s = blockIdx.x / nchunk;
    int c = blockIdx.x % nchunk;
    int base = c * CHUNK;
    int lim = n - base; if (lim > CHUNK) lim = CHUNK;
    __shared__ int hh[CHUNK];
    for (int i = threadIdx.x; i < lim; i += HBLK) hh[i] = 0;
    __syncthreads();
    int lo = s * slice_sz;
    int hi = lo + slice_sz; if (hi > Etot) hi = Etot;
    for (int j = lo + threadIdx.x; j < hi; j += HBLK) {
        int src, d;
        if (j < E) { src = ei[j]; d = ei[E + j]; } else { src = d = j - E; }
        int r = d - base;
        if (r >= 0 && r < lim) {
            int lrank = atomicAdd(&hh[r], 1);            // LDS atomic with return
            col[ptr[d] + off[s * n + d] + lrank] = src;
        }
    }
}

// ---------- fused GAT aggregation (h in bf16, 4 edges/iter quarter-waves) ----------
__global__ void k_gat_gather(const int* __restrict__ ptr, const int* __restrict__ col,
                             const unsigned short* __restrict__ h,
                             const float* __restrict__ alp_s, const float* __restrict__ alp_d,
                             const float* __restrict__ bias, float* __restrict__ wbuf,
                             float* __restrict__ out, int n) {
    int node = blockIdx.x * 4 + (threadIdx.x >> 6);
    if (node >= n) return;
    int lane = threadIdx.x & 63;
    int beg = ptr[node], end = ptr[node + 1];
    int deg = end - beg;
    float ad = alp_d[node];

    // ---- phase A: e, wave-max, exp, denom ----
    float m = -3.4e38f;
    float e_reg = 0.f;
    int   c_reg = 0;
    if (deg <= 64) {
        if (lane < deg) {
            int s = col[beg + lane];
            c_reg = s;
            float e = alp_s[s] + ad;
            e = e > 0.f ? e : NEG_SLOPE * e;
            e_reg = e;
            m = e;
        }
    } else {
        for (int j = beg + lane; j < end; j += 64) {
            int s = col[j];
            float e = alp_s[s] + ad;
            e = e > 0.f ? e : NEG_SLOPE * e;
            wbuf[j] = e;
            m = fmaxf(m, e);
        }
    }
#pragma unroll
    for (int off = 32; off > 0; off >>= 1) m = fmaxf(m, __shfl_xor(m, off));

    float den = 0.f;
    if (deg <= 64) {
        float ee = (lane < deg) ? __expf(e_reg - m) : 0.f;
        e_reg = ee;
        den = ee;
    } else {
        for (int j = beg + lane; j < end; j += 64) {
            float ee = __expf(wbuf[j] - m);
            wbuf[j] = ee;
            den += ee;
        }
    }
#pragma unroll
    for (int off = 32; off > 0; off >>= 1) den += __shfl_xor(den, off);

    // ---- phase B: 4 edges/iter; quarter-wave (16 lanes) per edge ----
    const uint4* __restrict__ h4 = (const uint4*)h;
    int q = lane >> 4;              // 0..3: which edge of the group
    int l16 = lane & 15;
    float accA[4] = {0.f, 0.f, 0.f, 0.f};
    float accB[4] = {0.f, 0.f, 0.f, 0.f};
    if (deg <= 64) {
        for (int j = beg; j < end; j += 4) {
            int idx = j + q;
            int t = (idx < end) ? (idx - beg) : (deg - 1);
            int s = __shfl(c_reg, t);
            float w = __shfl(e_reg, t);
            if (idx >= end) w = 0.f;
            uint4 hv = h4[(size_t)s * 16 + l16];
            accA[0] = fmaf(w, bflo2f(hv.x), accA[0]);
            accA[1] = fmaf(w, bfhi2f(hv.x), accA[1]);
            accA[2] = fmaf(w, bflo2f(hv.y), accA[2]);
            accA[3] = fmaf(w, bfhi2f(hv.y), accA[3]);
            accB[0] = fmaf(w, bflo2f(hv.z), accB[0]);
            accB[1] = fmaf(w, bfhi2f(hv.z), accB[1]);
            accB[2] = fmaf(w, bflo2f(hv.w), accB[2]);
            accB[3] = fmaf(w, bfhi2f(hv.w), accB[3]);
        }
    } else {
        for (int j = beg; j < end; j += 4) {
            int idx = j + q;
            int ii = (idx < end) ? idx : (end - 1);
            int s = col[ii];
            float w = (idx < end) ? wbuf[ii] : 0.f;
            uint4 hv = h4[(size_t)s * 16 + l16];
            accA[0] = fmaf(w, bflo2f(hv.x), accA[0]);
            accA[1] = fmaf(w, bfhi2f(hv.x), accA[1]);
            accA[2] = fmaf(w, bflo2f(hv.y), accA[2]);
            accA[3] = fmaf(w, bfhi2f(hv.y), accA[3]);
            accB[0] = fmaf(w, bflo2f(hv.z), accB[0]);
            accB[1] = fmaf(w, bfhi2f(hv.z), accB[1]);
            accB[2] = fmaf(w, bflo2f(hv.w), accB[2]);
            accB[3] = fmaf(w, bfhi2f(hv.w), accB[3]);
        }
    }
#pragma unroll
    for (int r = 0; r < 4; ++r) {
        accA[r] += __shfl_xor(accA[r], 16);
        accA[r] += __shfl_xor(accA[r], 32);
        accB[r] += __shfl_xor(accB[r], 16);
        accB[r] += __shfl_xor(accB[r], 32);
    }

    if (q == 0) {
        float inv = 1.f / den;
        const float4* b4 = (const float4*)bias;
        float4 bb0 = b4[l16 * 2];
        float4 bb1 = b4[l16 * 2 + 1];
        float4 o0, o1;
        o0.x = fmaf(accA[0], inv, bb0.x); o0.x = o0.x > 0.f ? o0.x : 0.f;
        o0.y = fmaf(accA[1], inv, bb0.y); o0.y = o0.y > 0.f ? o0.y : 0.f;
        o0.z = fmaf(accA[2], inv, bb0.z); o0.z = o0.z > 0.f ? o0.z : 0.f;
        o0.w = fmaf(accA[3], inv, bb0.w); o0.w = o0.w > 0.f ? o0.w : 0.f;
        o1.x = fmaf(accB[0], inv, bb1.x); o1.x = o1.x > 0.f ? o1.x : 0.f;
        o1.y = fmaf(accB[1], inv, bb1.y); o1.y = o1.y > 0.f ? o1.y : 0.f;
        o1.z = fmaf(accB[2], inv, bb1.z); o1.z = o1.z > 0.f ? o1.z : 0.f;
        o1.w = fmaf(accB[3], inv, bb1.w); o1.w = o1.w > 0.f ? o1.w : 0.f;
        float4* o4 = (float4*)out;
        o4[(size_t)node * 32 + l16 * 2]     = o0;
        o4[(size_t)node * 32 + l16 * 2 + 1] = o1;
    }
}

// ---------- graph boundaries via binary search on sorted batch ----------
__global__ void k_gptr(const int* __restrict__ batch, int* __restrict__ gptr, int n, int G) {
    int g = threadIdx.x;
    if (g > G) return;
    if (g == G) { gptr[G] = n; return; }
    int lo = 0, hi = n;
    while (lo < hi) {
        int mid = (lo + hi) >> 1;
        if (batch[mid] < g) lo = mid + 1; else hi = mid;
    }
    gptr[g] = lo;
}

// ---------- parallel mean pool: chunked partial sums, flush on graph change ----------
__global__ void k_pool_part(const float* __restrict__ x, const int* __restrict__ batch,
                            float* __restrict__ pooled, int n) {
    int r0 = blockIdx.x * PROWS;
    int t = threadIdx.x;            // 0..255
    int ch = t & (HD - 1);
    int rg = t >> 7;                // 0,1
    int rend = r0 + PROWS; if (rend > n) rend = n;
    float acc = 0.f;
    int curg = -1;
    for (int r = r0 + rg; r < rend; r += 2) {
        int g = batch[r];
        if (g != curg) {
            if (curg >= 0) atomicAdd(&pooled[curg * HD + ch], acc);
            curg = g;
            acc = 0.f;
        }
        acc += x[r * HD + ch];
    }
    if (curg >= 0) atomicAdd(&pooled[curg * HD + ch], acc);
}

__global__ void k_pool_div(float* __restrict__ pooled, const int* __restrict__ gptr, int total) {
    int i = blockIdx.x * blockDim.x + threadIdx.x;
    if (i >= total) return;
    int g = i >> 7;                 // /HD
    float cnt = (float)(gptr[g + 1] - gptr[g]);
    cnt = cnt < 1.f ? 1.f : cnt;
    pooled[i] /= cnt;
}

// ---------- doc embedding: relu(doc @ W_doc + b_doc) ----------
__global__ void k_doc(const float* __restrict__ doc, const float* __restrict__ Wd,
                      const float* __restrict__ bd, float* __restrict__ emb) {
    int g = blockIdx.x;
    int t = threadIdx.x;            // 0..127
    __shared__ float ds[DDOC];
    for (int k = t; k < DDOC; k += HD) ds[k] = doc[g * DDOC + k];
    __syncthreads();
    float acc = bd[t];
    for (int k = 0; k < DDOC; ++k) acc += ds[k] * Wd[k * HD + t];
    emb[g * HD + t] = acc > 0.f ? acc : 0.f;
}

// ---------- heads ----------
__global__ void k_head(const float* __restrict__ pooled, const float* __restrict__ emb,
                       const float* __restrict__ Wt, const float* __restrict__ bt,
                       const float* __restrict__ Wm, const float* __restrict__ bm,
                       float* __restrict__ out_task, float* __restrict__ out_time) {
    int g = blockIdx.x;
    int t = threadIdx.x;            // 0..63
    __shared__ float z[2 * HD];
    for (int k = t; k < HD; k += 64) {
        z[k] = pooled[g * HD + k];
        z[HD + k] = emb[g * HD + k];
    }
    __syncthreads();
    if (t < TOUT) {
        float acc = bt[t];
        for (int k = 0; k < 2 * HD; ++k) acc += z[k] * Wt[k * TOUT + t];
        out_task[g * TOUT + t] = acc;
    } else if (t == TOUT) {
        float acc = bm[0];
        for (int k = 0; k < 2 * HD; ++k) acc += z[k] * Wm[k];
        out_time[g] = acc;
    }
}

extern "C" void kernel_launch(void* const* d_in, const int* in_sizes, int n_in,
                              void* d_out, int out_size, void* d_ws, size_t ws_size,
                              hipStream_t stream) {
    const float* x0    = (const float*)d_in[0];
    const int*   ei    = (const int*)d_in[1];
    const int*   batch = (const int*)d_in[2];
    const float* doc   = (const float*)d_in[3];
    const float* W[3]   = {(const float*)d_in[4],  (const float*)d_in[8],  (const float*)d_in[12]};
    const float* a_s[3] = {(const float*)d_in[5],  (const float*)d_in[9],  (const float*)d_in[13]};
    const float* a_d[3] = {(const float*)d_in[6],  (const float*)d_in[10], (const float*)d_in[14]};
    const float* b[3]   = {(const float*)d_in[7],  (const float*)d_in[11], (const float*)d_in[15]};
    const float* Wdoc  = (const float*)d_in[16];
    const float* bdoc  = (const float*)d_in[17];
    const float* Wtask = (const float*)d_in[18];
    const float* btask = (const float*)d_in[19];
    const float* Wtime = (const float*)d_in[20];
    const float* btime = (const float*)d_in[21];

    const int N    = in_sizes[2];
    const int E    = in_sizes[1] / 2;
    const int Etot = E + N;
    const int G    = in_sizes[3] / DDOC;

    // workspace layout
    float* ws = (float*)d_ws;
    float* A      = ws; ws += (size_t)N * HD;   // layer output / next input (fp32)
    unsigned short* Hb = (unsigned short*)ws; ws += (size_t)N * HD / 2;  // h (bf16)
    float* alp_s  = ws; ws += N;
    float* alp_d  = ws; ws += N;
    float* wbuf   = ws; ws += Etot;             // fallback softmax weights (deg>64)
    float* pooled = ws; ws += (size_t)G * HD;
    float* emb    = ws; ws += (size_t)G * HD;
    int* cnt    = (int*)ws; ws += (size_t)NSLICE * N;
    int* off    = (int*)ws; ws += (size_t)NSLICE * N;
    int* deg    = (int*)ws; ws += N;
    int* ptr    = (int*)ws; ws += N + 1;
    int* gptr   = (int*)ws; ws += G + 1;
    int* bsum   = (int*)ws; ws += SCANB;
    int* col    = (int*)ws; ws += Etot;

    float* out_task = (float*)d_out;
    float* out_time = out_task + (size_t)G * TOUT;

    const int thr = 256;
    const int nBlocks = (N + thr - 1) / thr;
    const int sBlocks = (N + SCANB - 1) / SCANB;   // 118 <= SCANB
    const int nchunk  = (N + CHUNK - 1) / CHUNK;   // 2
    const int slice_sz = (Etot + NSLICE - 1) / NSLICE;
    const int csrBlocks = NSLICE * nchunk;         // 32

    // ---- build CSR (dst-sorted adjacency), zero global atomics ----
    k_init<<<(G * HD + thr - 1) / thr, thr, 0, stream>>>(pooled, G * HD);
    k_hist_lds<<<csrBlocks, HBLK, 0, stream>>>(ei, E, Etot, N, slice_sz, nchunk, cnt);
    k_nodeoff<<<nBlocks, thr, 0, stream>>>(cnt, off, deg, N);
    k_scan_part<<<sBlocks, SCANB, 0, stream>>>(deg, bsum, N);
    k_scan_bsum<<<1, SCANB, 0, stream>>>(bsum, sBlocks);
    k_scan_final<<<sBlocks, SCANB, 0, stream>>>(deg, bsum, ptr, N, Etot);
    k_fill_lds<<<csrBlocks, HBLK, 0, stream>>>(ei, E, Etot, N, slice_sz, nchunk, ptr, off, col);

    // ---- graph boundaries ----
    k_gptr<<<1, G + 1, 0, stream>>>(batch, gptr, N, G);

    // ---- 3 GAT layers ----
    const float* xin = x0;
    for (int l = 0; l < 3; ++l) {
        k_gemm_alpha<<<(N + RB - 1) / RB, thr, 0, stream>>>(xin, W[l], a_s[l], a_d[l],
                                                            Hb, alp_s, alp_d, N);
        k_gat_gather<<<(N + 3) / 4, thr, 0, stream>>>(ptr, col, Hb, alp_s, alp_d, b[l],
                                                      wbuf, A, N);
        xin = A;
    }

    // ---- global mean pool (parallel partials + divide) ----
    k_pool_part<<<(N + PROWS - 1) / PROWS, thr, 0, stream>>>(A, batch, pooled, N);
    k_pool_div<<<(G * HD + thr - 1) / thr, thr, 0, stream>>>(pooled, gptr, G * HD);

    // ---- doc embedding + heads ----
    k_doc<<<G, HD, 0, stream>>>(doc, Wdoc, bdoc, emb);
    k_head<<<G, 64, 0, stream>>>(pooled, emb, Wtask, btask, Wtime, btime,
                                 out_task, out_time);
}

// Round 10
// 261.979 us; speedup vs baseline: 1.2001x; 1.2001x over previous
//
#include <hip/hip_runtime.h>

#define HD 128          // hidden dim (== DIN)
#define DDOC 512
#define TOUT 32
#define RB 16           // rows per block in gemm
#define SCANB 256
#define PROWS 64        // rows per block in pooling
constexpr float NEG_SLOPE = 0.2f;

// ---------- bf16 helpers ----------
__device__ __forceinline__ unsigned short f2bf(float f) {
    unsigned int b = __float_as_uint(f);
    b += 0x7fffu + ((b >> 16) & 1u);     // round-to-nearest-even
    return (unsigned short)(b >> 16);
}
__device__ __forceinline__ float bflo2f(unsigned int u) { return __uint_as_float(u << 16); }
__device__ __forceinline__ float bfhi2f(unsigned int u) { return __uint_as_float(u & 0xffff0000u); }
__device__ __forceinline__ unsigned int pk2bf(float lo, float hi) {
    return (unsigned int)f2bf(lo) | ((unsigned int)f2bf(hi) << 16);
}

// ---------- prep: zero deg+pooled, compute gptr via binary search ----------
__global__ void k_prep(const int* __restrict__ batch, int* __restrict__ gptr,
                       float* __restrict__ pooled, int* __restrict__ deg, int n, int G) {
    int i = blockIdx.x * blockDim.x + threadIdx.x;
    if (i < G * HD) pooled[i] = 0.f;
    if (i < n) deg[i] = 0;
    if (i <= G) {
        if (i == G) { gptr[G] = n; }
        else {
            int lo = 0, hi = n;
            while (lo < hi) {
                int mid = (lo + hi) >> 1;
                if (batch[mid] < i) lo = mid + 1; else hi = mid;
            }
            gptr[i] = lo;
        }
    }
}

// ---------- tiled GEMM + fused alpha: h = x@W (bf16 out), alpha = h.a (fp32) ----------
template <bool BF16IN>
__global__ void k_gemm_alpha(const void* __restrict__ xin, const float* __restrict__ W,
                             const float* __restrict__ av_s, const float* __restrict__ av_d,
                             unsigned short* __restrict__ h, float* __restrict__ alp_s,
                             float* __restrict__ alp_d, int n) {
    int row0 = blockIdx.x * RB;
    int t = threadIdx.x;            // 0..255
    int c = t & (HD - 1);
    int rg = t >> 7;                // 0: rows 0-7, 1: rows 8-15

    __shared__ float xs[RB][HD];
    {   // staging: each thread loads 8 contiguous channels of one row
        int idx = t * 8;
        int r = idx >> 7, k = idx & (HD - 1);
        int row = row0 + r;
        if (row < n) {
            if (BF16IN) {
                const unsigned short* xb = (const unsigned short*)xin;
                uint4 v = *(const uint4*)&xb[(size_t)row * HD + k];
                xs[r][k + 0] = bflo2f(v.x); xs[r][k + 1] = bfhi2f(v.x);
                xs[r][k + 2] = bflo2f(v.y); xs[r][k + 3] = bfhi2f(v.y);
                xs[r][k + 4] = bflo2f(v.z); xs[r][k + 5] = bfhi2f(v.z);
                xs[r][k + 6] = bflo2f(v.w); xs[r][k + 7] = bfhi2f(v.w);
            } else {
                const float* xf = (const float*)xin;
                float4 v0 = *(const float4*)&xf[(size_t)row * HD + k];
                float4 v1 = *(const float4*)&xf[(size_t)row * HD + k + 4];
                xs[r][k + 0] = v0.x; xs[r][k + 1] = v0.y;
                xs[r][k + 2] = v0.z; xs[r][k + 3] = v0.w;
                xs[r][k + 4] = v1.x; xs[r][k + 5] = v1.y;
                xs[r][k + 6] = v1.z; xs[r][k + 7] = v1.w;
            }
        } else {
#pragma unroll
            for (int j = 0; j < 8; ++j) xs[r][k + j] = 0.f;
        }
    }
    __syncthreads();

    float acc[8] = {0.f, 0.f, 0.f, 0.f, 0.f, 0.f, 0.f, 0.f};
    for (int k = 0; k < HD; ++k) {
        float w = W[k * HD + c];
#pragma unroll
        for (int r = 0; r < 8; ++r) acc[r] = fmaf(xs[rg * 8 + r][k], w, acc[r]);
    }
#pragma unroll
    for (int r = 0; r < 8; ++r) {
        int row = row0 + rg * 8 + r;
        if (row < n) h[row * HD + c] = f2bf(acc[r]);
    }

    float as = av_s[c], ad = av_d[c];
    __shared__ float redS[4][8], redD[4][8];
    int wave = t >> 6, lane = t & 63;
#pragma unroll
    for (int r = 0; r < 8; ++r) {
        float vs = acc[r] * as;
        float vd = acc[r] * ad;
#pragma unroll
        for (int off = 32; off > 0; off >>= 1) {
            vs += __shfl_xor(vs, off);
            vd += __shfl_xor(vd, off);
        }
        if (lane == 0) { redS[wave][r] = vs; redD[wave][r] = vd; }
    }
    __syncthreads();
    if (t < RB) {
        int w0 = (t < 8) ? 0 : 2;
        int rr = t & 7;
        int row = row0 + t;
        if (row < n) {
            alp_s[row] = redS[w0][rr] + redS[w0 + 1][rr];
            alp_d[row] = redD[w0][rr] + redD[w0 + 1][rr];
        }
    }
}

// ---------- CSR build: hist captures per-edge rank (one atomic pass total) ----------
__global__ void k_hist(const int* __restrict__ ei, int E, int Etot,
                       int* __restrict__ deg, int* __restrict__ rank) {
    int i = blockIdx.x * blockDim.x + threadIdx.x;
    if (i >= Etot) return;
    int d = (i < E) ? ei[E + i] : (i - E);
    rank[i] = atomicAdd(&deg[d], 1);
}

// ---------- 3-phase device-wide exclusive scan of deg -> ptr ----------
__global__ void k_scan_part(const int* __restrict__ deg, int* __restrict__ bsum, int n) {
    int t = threadIdx.x;
    int i = blockIdx.x * SCANB + t;
    int v = (i < n) ? deg[i] : 0;
#pragma unroll
    for (int off = 32; off > 0; off >>= 1) v += __shfl_xor(v, off);
    __shared__ int red[4];
    if ((t & 63) == 0) red[t >> 6] = v;
    __syncthreads();
    if (t == 0) bsum[blockIdx.x] = red[0] + red[1] + red[2] + red[3];
}

__global__ void k_scan_bsum(int* __restrict__ bsum, int nb) {
    __shared__ int part[SCANB];
    int t = threadIdx.x;
    int v = (t < nb) ? bsum[t] : 0;
    part[t] = v;
    __syncthreads();
    for (int off = 1; off < SCANB; off <<= 1) {
        int u = (t >= off) ? part[t - off] : 0;
        __syncthreads();
        part[t] += u;
        __syncthreads();
    }
    if (t < nb) bsum[t] = part[t] - v;   // exclusive
}

__global__ void k_scan_final(const int* __restrict__ deg, const int* __restrict__ bsum,
                             int* __restrict__ ptr, int n, int total) {
    __shared__ int part[SCANB];
    int t = threadIdx.x;
    int i = blockIdx.x * SCANB + t;
    int v = (i < n) ? deg[i] : 0;
    part[t] = v;
    __syncthreads();
    for (int off = 1; off < SCANB; off <<= 1) {
        int u = (t >= off) ? part[t - off] : 0;
        __syncthreads();
        part[t] += u;
        __syncthreads();
    }
    if (i < n) ptr[i] = bsum[blockIdx.x] + part[t] - v;
    if (i == n - 1) ptr[n] = total;
}

// ---------- fill: atomic-free, pos = ptr[d] + rank[i] ----------
__global__ void k_fill(const int* __restrict__ ei, int E, int Etot,
                       const int* __restrict__ ptr, const int* __restrict__ rank,
                       int* __restrict__ col) {
    int i = blockIdx.x * blockDim.x + threadIdx.x;
    if (i >= Etot) return;
    int s, d;
    if (i < E) { s = ei[i]; d = ei[E + i]; } else { s = d = i - E; }
    col[ptr[d] + rank[i]] = s;
}

// ---------- fused GAT aggregation (h bf16 in, A bf16 out, quarter-wave phase B) ----------
__global__ void k_gat_gather(const int* __restrict__ ptr, const int* __restrict__ col,
                             const unsigned short* __restrict__ h,
                             const float* __restrict__ alp_s, const float* __restrict__ alp_d,
                             const float* __restrict__ bias, float* __restrict__ wbuf,
                             unsigned short* __restrict__ out, int n) {
    int node = blockIdx.x * 4 + (threadIdx.x >> 6);
    if (node >= n) return;
    int lane = threadIdx.x & 63;
    int beg = ptr[node], end = ptr[node + 1];
    int deg = end - beg;
    float ad = alp_d[node];

    // ---- phase A: e, wave-max, exp, denom ----
    float m = -3.4e38f;
    float e_reg = 0.f;
    int   c_reg = 0;
    if (deg <= 64) {
        if (lane < deg) {
            int s = col[beg + lane];
            c_reg = s;
            float e = alp_s[s] + ad;
            e = e > 0.f ? e : NEG_SLOPE * e;
            e_reg = e;
            m = e;
        }
    } else {
        for (int j = beg + lane; j < end; j += 64) {
            int s = col[j];
            float e = alp_s[s] + ad;
            e = e > 0.f ? e : NEG_SLOPE * e;
            wbuf[j] = e;
            m = fmaxf(m, e);
        }
    }
#pragma unroll
    for (int off = 32; off > 0; off >>= 1) m = fmaxf(m, __shfl_xor(m, off));

    float den = 0.f;
    if (deg <= 64) {
        float ee = (lane < deg) ? __expf(e_reg - m) : 0.f;
        e_reg = ee;
        den = ee;
    } else {
        for (int j = beg + lane; j < end; j += 64) {
            float ee = __expf(wbuf[j] - m);
            wbuf[j] = ee;
            den += ee;
        }
    }
#pragma unroll
    for (int off = 32; off > 0; off >>= 1) den += __shfl_xor(den, off);

    // ---- phase B: 4 edges/iter; quarter-wave (16 lanes) per edge ----
    const uint4* __restrict__ h4 = (const uint4*)h;
    int q = lane >> 4;              // 0..3: which edge of the group
    int l16 = lane & 15;
    float accA[4] = {0.f, 0.f, 0.f, 0.f};
    float accB[4] = {0.f, 0.f, 0.f, 0.f};
    if (deg <= 64) {
        for (int j = beg; j < end; j += 4) {
            int idx = j + q;
            int t = (idx < end) ? (idx - beg) : (deg - 1);
            int s = __shfl(c_reg, t);
            float w = __shfl(e_reg, t);
            if (idx >= end) w = 0.f;
            uint4 hv = h4[(size_t)s * 16 + l16];
            accA[0] = fmaf(w, bflo2f(hv.x), accA[0]);
            accA[1] = fmaf(w, bfhi2f(hv.x), accA[1]);
            accA[2] = fmaf(w, bflo2f(hv.y), accA[2]);
            accA[3] = fmaf(w, bfhi2f(hv.y), accA[3]);
            accB[0] = fmaf(w, bflo2f(hv.z), accB[0]);
            accB[1] = fmaf(w, bfhi2f(hv.z), accB[1]);
            accB[2] = fmaf(w, bflo2f(hv.w), accB[2]);
            accB[3] = fmaf(w, bfhi2f(hv.w), accB[3]);
        }
    } else {
        for (int j = beg; j < end; j += 4) {
            int idx = j + q;
            int ii = (idx < end) ? idx : (end - 1);
            int s = col[ii];
            float w = (idx < end) ? wbuf[ii] : 0.f;
            uint4 hv = h4[(size_t)s * 16 + l16];
            accA[0] = fmaf(w, bflo2f(hv.x), accA[0]);
            accA[1] = fmaf(w, bfhi2f(hv.x), accA[1]);
            accA[2] = fmaf(w, bflo2f(hv.y), accA[2]);
            accA[3] = fmaf(w, bfhi2f(hv.y), accA[3]);
            accB[0] = fmaf(w, bflo2f(hv.z), accB[0]);
            accB[1] = fmaf(w, bfhi2f(hv.z), accB[1]);
            accB[2] = fmaf(w, bflo2f(hv.w), accB[2]);
            accB[3] = fmaf(w, bfhi2f(hv.w), accB[3]);
        }
    }
#pragma unroll
    for (int r = 0; r < 4; ++r) {
        accA[r] += __shfl_xor(accA[r], 16);
        accA[r] += __shfl_xor(accA[r], 32);
        accB[r] += __shfl_xor(accB[r], 16);
        accB[r] += __shfl_xor(accB[r], 32);
    }

    if (q == 0) {
        float inv = 1.f / den;
        const float4* b4 = (const float4*)bias;
        float4 bb0 = b4[l16 * 2];
        float4 bb1 = b4[l16 * 2 + 1];
        float o[8];
        o[0] = fmaf(accA[0], inv, bb0.x); o[1] = fmaf(accA[1], inv, bb0.y);
        o[2] = fmaf(accA[2], inv, bb0.z); o[3] = fmaf(accA[3], inv, bb0.w);
        o[4] = fmaf(accB[0], inv, bb1.x); o[5] = fmaf(accB[1], inv, bb1.y);
        o[6] = fmaf(accB[2], inv, bb1.z); o[7] = fmaf(accB[3], inv, bb1.w);
#pragma unroll
        for (int r = 0; r < 8; ++r) o[r] = o[r] > 0.f ? o[r] : 0.f;
        uint4 pk;
        pk.x = pk2bf(o[0], o[1]); pk.y = pk2bf(o[2], o[3]);
        pk.z = pk2bf(o[4], o[5]); pk.w = pk2bf(o[6], o[7]);
        ((uint4*)out)[(size_t)node * 16 + l16] = pk;
    }
}

// ---------- parallel mean pool over bf16 A: partials, flush on graph change ----------
__global__ void k_pool_part(const unsigned short* __restrict__ x, const int* __restrict__ batch,
                            float* __restrict__ pooled, int n) {
    int r0 = blockIdx.x * PROWS;
    int t = threadIdx.x;            // 0..255
    int cp = t & 63;                // channel pair (2*cp, 2*cp+1)
    int rg = t >> 6;                // 0..3
    int rend = r0 + PROWS; if (rend > n) rend = n;
    float a0 = 0.f, a1 = 0.f;
    int curg = -1;
    for (int r = r0 + rg; r < rend; r += 4) {
        int g = batch[r];
        if (g != curg) {
            if (curg >= 0) {
                atomicAdd(&pooled[curg * HD + 2 * cp], a0);
                atomicAdd(&pooled[curg * HD + 2 * cp + 1], a1);
            }
            curg = g;
            a0 = a1 = 0.f;
        }
        unsigned int u = ((const unsigned int*)(x + (size_t)r * HD))[cp];
        a0 += bflo2f(u);
        a1 += bfhi2f(u);
    }
    if (curg >= 0) {
        atomicAdd(&pooled[curg * HD + 2 * cp], a0);
        atomicAdd(&pooled[curg * HD + 2 * cp + 1], a1);
    }
}

// ---------- fused doc-embedding + mean-div + heads (one block per graph) ----------
__global__ void k_head(const float* __restrict__ pooled, const int* __restrict__ gptr,
                       const float* __restrict__ doc, const float* __restrict__ Wd,
                       const float* __restrict__ bd,
                       const float* __restrict__ Wt, const float* __restrict__ bt,
                       const float* __restrict__ Wm, const float* __restrict__ bm,
                       float* __restrict__ out_task, float* __restrict__ out_time) {
    int g = blockIdx.x;
    int t = threadIdx.x;            // 0..127
    __shared__ float ds[DDOC];
    __shared__ float z[2 * HD];
    for (int k = t; k < DDOC; k += HD) ds[k] = doc[g * DDOC + k];
    float cnt = (float)(gptr[g + 1] - gptr[g]);
    cnt = cnt < 1.f ? 1.f : cnt;
    z[t] = pooled[g * HD + t] / cnt;
    __syncthreads();
    float acc = bd[t];
    for (int k = 0; k < DDOC; ++k) acc = fmaf(ds[k], Wd[k * HD + t], acc);
    z[HD + t] = acc > 0.f ? acc : 0.f;
    __syncthreads();
    if (t < TOUT) {
        float a = bt[t];
        for (int k = 0; k < 2 * HD; ++k) a = fmaf(z[k], Wt[k * TOUT + t], a);
        out_task[g * TOUT + t] = a;
    } else if (t == TOUT) {
        float a = bm[0];
        for (int k = 0; k < 2 * HD; ++k) a = fmaf(z[k], Wm[k], a);
        out_time[g] = a;
    }
}

extern "C" void kernel_launch(void* const* d_in, const int* in_sizes, int n_in,
                              void* d_out, int out_size, void* d_ws, size_t ws_size,
                              hipStream_t stream) {
    const float* x0    = (const float*)d_in[0];
    const int*   ei    = (const int*)d_in[1];
    const int*   batch = (const int*)d_in[2];
    const float* doc   = (const float*)d_in[3];
    const float* W[3]   = {(const float*)d_in[4],  (const float*)d_in[8],  (const float*)d_in[12]};
    const float* a_s[3] = {(const float*)d_in[5],  (const float*)d_in[9],  (const float*)d_in[13]};
    const float* a_d[3] = {(const float*)d_in[6],  (const float*)d_in[10], (const float*)d_in[14]};
    const float* b[3]   = {(const float*)d_in[7],  (const float*)d_in[11], (const float*)d_in[15]};
    const float* Wdoc  = (const float*)d_in[16];
    const float* bdoc  = (const float*)d_in[17];
    const float* Wtask = (const float*)d_in[18];
    const float* btask = (const float*)d_in[19];
    const float* Wtime = (const float*)d_in[20];
    const float* btime = (const float*)d_in[21];

    const int N    = in_sizes[2];
    const int E    = in_sizes[1] / 2;
    const int Etot = E + N;
    const int G    = in_sizes[3] / DDOC;

    // workspace layout
    float* ws = (float*)d_ws;
    unsigned short* A  = (unsigned short*)ws; ws += (size_t)N * HD / 2;  // layer output (bf16)
    unsigned short* Hb = (unsigned short*)ws; ws += (size_t)N * HD / 2;  // h (bf16)
    float* alp_s  = ws; ws += N;
    float* alp_d  = ws; ws += N;
    float* wbuf   = ws; ws += Etot;             // fallback softmax weights (deg>64)
    float* pooled = ws; ws += (size_t)G * HD;
    int* deg    = (int*)ws; ws += N;
    int* rank   = (int*)ws; ws += Etot;
    int* ptr    = (int*)ws; ws += N + 1;
    int* gptr   = (int*)ws; ws += G + 1;
    int* bsum   = (int*)ws; ws += SCANB;
    int* col    = (int*)ws; ws += Etot;

    float* out_task = (float*)d_out;
    float* out_time = out_task + (size_t)G * TOUT;

    const int thr = 256;
    const int eBlocks = (Etot + thr - 1) / thr;
    const int sBlocks = (N + SCANB - 1) / SCANB;   // 118 <= SCANB
    int prepN = N > G * HD ? N : G * HD;

    // ---- prep (zero deg/pooled, gptr) + CSR build ----
    k_prep<<<(prepN + thr - 1) / thr, thr, 0, stream>>>(batch, gptr, pooled, deg, N, G);
    k_hist<<<eBlocks, thr, 0, stream>>>(ei, E, Etot, deg, rank);
    k_scan_part<<<sBlocks, SCANB, 0, stream>>>(deg, bsum, N);
    k_scan_bsum<<<1, SCANB, 0, stream>>>(bsum, sBlocks);
    k_scan_final<<<sBlocks, SCANB, 0, stream>>>(deg, bsum, ptr, N, Etot);
    k_fill<<<eBlocks, thr, 0, stream>>>(ei, E, Etot, ptr, rank, col);

    // ---- 3 GAT layers ----
    const int gBlocks = (N + RB - 1) / RB;
    const int aBlocks = (N + 3) / 4;
    k_gemm_alpha<false><<<gBlocks, thr, 0, stream>>>(x0, W[0], a_s[0], a_d[0],
                                                     Hb, alp_s, alp_d, N);
    k_gat_gather<<<aBlocks, thr, 0, stream>>>(ptr, col, Hb, alp_s, alp_d, b[0], wbuf, A, N);
    for (int l = 1; l < 3; ++l) {
        k_gemm_alpha<true><<<gBlocks, thr, 0, stream>>>(A, W[l], a_s[l], a_d[l],
                                                        Hb, alp_s, alp_d, N);
        k_gat_gather<<<aBlocks, thr, 0, stream>>>(ptr, col, Hb, alp_s, alp_d, b[l], wbuf, A, N);
    }

    // ---- global mean pool (parallel partials; divide fused into head) ----
    k_pool_part<<<(N + PROWS - 1) / PROWS, thr, 0, stream>>>(A, batch, pooled, N);

    // ---- fused doc embedding + heads ----
    k_head<<<G, HD, 0, stream>>>(pooled, gptr, doc, Wdoc, bdoc,
                                 Wtask, btask, Wtime, btime, out_task, out_time);
}